// Round 10
// baseline (1187.557 us; speedup 1.0000x reference)
//
#include <hip/hip_runtime.h>
#include <cmath>

// Problem constants
#define M 256
#define N 512
#define P 24
#define D 8

// ---------------------------------------------------------------------------
// self terms + folded weights at[i,u] = A[i,u]*exp(-0.5*||x_iu||^2).
// Block M+N writes the ones-column of Bc.
// ---------------------------------------------------------------------------
__global__ __launch_bounds__(64) void self_kernel(const float* __restrict__ X_test,
                                                  const float* __restrict__ A_test,
                                                  const float* __restrict__ X_obs,
                                                  const float* __restrict__ A_obs,
                                                  float* __restrict__ s1,
                                                  float* __restrict__ s2,
                                                  float* __restrict__ atT,
                                                  float* __restrict__ atO,
                                                  double* __restrict__ Bc) {
    const int bid = blockIdx.x;
    const int lane = threadIdx.x;
    if (bid == M + N) {  // ones column (col 256 of Bc, col-major [257][512])
#pragma unroll
        for (int t = 0; t < 8; ++t) Bc[(size_t)256 * 512 + 64 * t + lane] = 1.0;
        return;
    }
    const float* X; const float* A; float* s; float* at; int i;
    if (bid < M) { X = X_test; A = A_test; s = s1; at = atT; i = bid; }
    else         { X = X_obs;  A = A_obs;  s = s2; at = atO; i = bid - M; }
    const float* Xi = X + (size_t)i * P * D;
    const float* Ai = A + (size_t)i * P;
    float acc = 0.f;
#pragma unroll
    for (int t = 0; t < 9; ++t) {
        int idx = lane + 64 * t;          // 0..575
        int u = idx / 24;
        int v = idx - u * 24;
        const float* xu = Xi + u * D;
        const float* xv = Xi + v * D;
        float d2 = 0.f;
#pragma unroll
        for (int d = 0; d < D; ++d) { float df = xu[d] - xv[d]; d2 = fmaf(df, df, d2); }
        acc = fmaf(Ai[u] * Ai[v], __expf(-0.5f * d2), acc);
    }
#pragma unroll
    for (int off = 1; off < 64; off <<= 1) acc += __shfl_xor(acc, off, 64);
    if (lane == 0) s[i] = acc;
    if (lane < 24) {
        const float* xp = Xi + lane * D;
        float q = 0.f;
#pragma unroll
        for (int d = 0; d < D; ++d) q = fmaf(xp[d], xp[d], q);
        at[(size_t)i * P + lane] = Ai[lane] * __expf(-0.5f * q);
    }
}

// ---------------------------------------------------------------------------
// fused gram kernel with norm-folded weights (unchanged)
// ---------------------------------------------------------------------------
__global__ __launch_bounds__(128) void gram_kernel(
    const float* __restrict__ Xt, const float* __restrict__ atT, const float* __restrict__ s1,
    const float* __restrict__ Xo, const float* __restrict__ atO, const float* __restrict__ s2,
    const float* __restrict__ rho_p, const float* __restrict__ nu_p, const float* __restrict__ g_p,
    float* __restrict__ Kox, float* __restrict__ Kxx, double* __restrict__ Koo,
    double* __restrict__ Bc) {
    const int mode = blockIdx.z;
    const int it = blockIdx.x, jt = blockIdx.y;
    const float *X1, *AT1, *S1, *X2, *AT2, *S2;
    if (mode == 0) {
        if (jt > 2 * it + 1) return;
        X1 = Xo; AT1 = atO; S1 = s2; X2 = Xo; AT2 = atO; S2 = s2;
    } else if (mode == 1) {
        if (jt >= 32) return;
        X1 = Xo; AT1 = atO; S1 = s2; X2 = Xt; AT2 = atT; S2 = s1;
    } else {
        if (it >= 16 || jt >= 32 || jt < 2 * it) return;
        X1 = Xt; AT1 = atT; S1 = s1; X2 = Xt; AT2 = atT; S2 = s1;
    }
    const int i0 = it * 16, j0 = jt * 8;
    const int tid = threadIdx.x;
    const int il = tid >> 3, uc = tid & 7;
    const int i = i0 + il;

    __shared__ __align__(16) float X2s[8 * 192];
    __shared__ float A2s[8 * 24];
    __shared__ float S2s[8];
    {
        const float4* gx = (const float4*)(X2 + (size_t)j0 * 192);
        float4* lx = (float4*)X2s;
        for (int idx = tid; idx < 8 * 48; idx += 128) lx[idx] = gx[idx];
        for (int idx = tid; idx < 8 * 24; idx += 128) A2s[idx] = AT2[(size_t)j0 * 24 + idx];
        if (tid < 8) S2s[tid] = S2[j0 + tid];
    }
    __syncthreads();

    float x1r[3][8], at1r[3];
#pragma unroll
    for (int ss = 0; ss < 3; ++ss) {
        const float* p = X1 + ((size_t)i * P + uc * 3 + ss) * D;
#pragma unroll
        for (int d = 0; d < D; ++d) x1r[ss][d] = p[d];
        at1r[ss] = AT1[(size_t)i * P + uc * 3 + ss];
    }
    const float s1i = S1[i];
    const float rho = rho_p[0], nu = nu_p[0], g = g_p[0];

    for (int jj = 0; jj < 8; ++jj) {
        const float* xb = X2s + jj * 192;
        float e0 = 0.f, e1 = 0.f, e2 = 0.f;
#pragma unroll 4
        for (int v = 0; v < 24; ++v) {
            const float4 q0 = ((const float4*)(xb + v * 8))[0];
            const float4 q1 = ((const float4*)(xb + v * 8))[1];
            float x2r[8];
            x2r[0] = q0.x; x2r[1] = q0.y; x2r[2] = q0.z; x2r[3] = q0.w;
            x2r[4] = q1.x; x2r[5] = q1.y; x2r[6] = q1.z; x2r[7] = q1.w;
            const float w2 = A2s[jj * 24 + v];
            float d0 = 0.f, d1 = 0.f, d2 = 0.f;
#pragma unroll
            for (int dd = 0; dd < 8; ++dd) {
                d0 = fmaf(x1r[0][dd], x2r[dd], d0);
                d1 = fmaf(x1r[1][dd], x2r[dd], d1);
                d2 = fmaf(x1r[2][dd], x2r[dd], d2);
            }
            e0 = fmaf(w2, __expf(d0), e0);
            e1 = fmaf(w2, __expf(d1), e1);
            e2 = fmaf(w2, __expf(d2), e2);
        }
        float acc = at1r[0] * e0;
        acc = fmaf(at1r[1], e1, acc);
        acc = fmaf(at1r[2], e2, acc);
        acc += __shfl_xor(acc, 1, 8);
        acc += __shfl_xor(acc, 2, 8);
        acc += __shfl_xor(acc, 4, 8);
        if (uc == 0) {
            const int j = j0 + jj;
            float d2p = fmaxf(s1i + S2s[jj] - 2.f * acc, 0.f);
            float kv = __expf(-0.5f * d2p / rho);
            if (mode == 0) {
                if (j <= i) Koo[(size_t)i * 512 + j] = (double)(nu * (kv + ((i == j) ? g : 0.f)));
            } else if (mode == 1) {
                float val = nu * kv;
                Kox[(size_t)i * 256 + j] = val;
                Bc[(size_t)j * 512 + i] = (double)val;
            } else {
                float val = nu * kv;
                if (j >= i) {
                    Kxx[(size_t)i * 256 + j] = val;
                    if (j > i) Kxx[(size_t)j * 256 + i] = val;
                }
            }
        }
    }
}

// ---------------------------------------------------------------------------
// factor64 v2: per-16x16-block serial work moved to REGISTERS of wave 0 with
// fully-unrolled steps (shfl-based broadcasts, no LDS round-trips in the
// dependent chain — r9 post-mortem: LDS-serial version cost ~85us/call).
// Produces L (lower, in sA), X = inv(L64) -> Dinv[p], DinvT[p], W diag tile.
// ---------------------------------------------------------------------------
__device__ void factor64(double (*sA)[65], double (*sX)[65], double* sW,
                         double* __restrict__ W,
                         double* __restrict__ Dinv,
                         double* __restrict__ DinvT,
                         int p) {
    const int tid = threadIdx.x;
    const int k0 = p * 64;
    {
        double* f = &sX[0][0];
        for (int idx = tid; idx < 64 * 65; idx += 256) f[idx] = 0.0;
    }
    __syncthreads();
    for (int q = 0; q < 4; ++q) {
        const int b0 = 16 * q;
        if (tid < 64) {
            // ---- in-register 16x16 Cholesky + inverse (wave 0) ----
            const int l = tid;
            const int rr = l >> 2;        // row 0..15
            const int gg = l & 3;         // col group: cols 4gg..4gg+3
            double a[4], x[4];
#pragma unroll
            for (int j = 0; j < 4; ++j) {
                int cc = 4 * gg + j;
                a[j] = (cc <= rr) ? sA[b0 + rr][b0 + cc] : sA[b0 + cc][b0 + rr];
                x[j] = 0.0;
            }
            // Cholesky, fully unrolled (slot & lane indices compile-time)
#pragma unroll
            for (int k = 0; k < 16; ++k) {
                double akk = __shfl(a[k & 3], (k << 2) | (k >> 2), 64);
                double rd = 1.0 / sqrt(akk);
                if (gg == (k >> 2) && rr >= k)
                    a[k & 3] = (rr == k) ? akk * rd : a[k & 3] * rd;
                if (k < 15) {
                    double lrk = __shfl(a[k & 3], (rr << 2) | (k >> 2), 64);
                    double lck[4];
#pragma unroll
                    for (int j = 0; j < 4; ++j)
                        lck[j] = __shfl(a[k & 3], ((4 * gg + j) << 2) | (k >> 2), 64);
#pragma unroll
                    for (int j = 0; j < 4; ++j) {
                        int cc = 4 * gg + j;
                        if (rr > k && cc > k) a[j] = fma(-lrk, lck[j], a[j]);
                    }
                }
            }
            // X = inv(L): row-serial forward substitution, fully unrolled
#pragma unroll
            for (int r2 = 0; r2 < 16; ++r2) {
                double s0 = 0.0, s1 = 0.0, s2 = 0.0, s3 = 0.0;
#pragma unroll
                for (int t = 0; t < r2; ++t) {
                    double lrt = __shfl(a[t & 3], (r2 << 2) | (t >> 2), 64);
                    s0 = fma(lrt, __shfl(x[0], (t << 2) | gg, 64), s0);
                    s1 = fma(lrt, __shfl(x[1], (t << 2) | gg, 64), s1);
                    s2 = fma(lrt, __shfl(x[2], (t << 2) | gg, 64), s2);
                    s3 = fma(lrt, __shfl(x[3], (t << 2) | gg, 64), s3);
                }
                double lrr = __shfl(a[r2 & 3], (r2 << 2) | (r2 >> 2), 64);
                double rdr = 1.0 / lrr;
                if (rr == r2) {
                    double sv[4] = {s0, s1, s2, s3};
#pragma unroll
                    for (int j = 0; j < 4; ++j) {
                        int cc = 4 * gg + j;
                        x[j] = (cc <= r2) ? (((cc == r2) ? 1.0 : 0.0) - sv[j]) * rdr : 0.0;
                    }
                }
            }
            // write back: L lower -> sA, X (with upper zeros) -> sX
#pragma unroll
            for (int j = 0; j < 4; ++j) {
                int cc = 4 * gg + j;
                if (cc <= rr) sA[b0 + rr][b0 + cc] = a[j];
                sX[b0 + rr][b0 + cc] = x[j];
            }
        }
        __syncthreads();
        if (q < 3) {
            const int nrows = 48 - b0;
            const int cells = nrows * 16;
            double tv[3];
#pragma unroll
            for (int ii = 0; ii < 3; ++ii) {
                int idx = tid + 256 * ii;
                tv[ii] = 0.0;
                if (idx < cells) {
                    int a2 = b0 + 16 + (idx >> 4), cc = idx & 15;
                    double acc = 0.0;
                    for (int t = 0; t <= cc; ++t)
                        acc = fma(sA[a2][b0 + t], sX[b0 + cc][b0 + t], acc);
                    tv[ii] = acc;
                }
            }
            __syncthreads();
#pragma unroll
            for (int ii = 0; ii < 3; ++ii) {
                int idx = tid + 256 * ii;
                if (idx < cells) {
                    int a2 = b0 + 16 + (idx >> 4), cc = idx & 15;
                    sA[a2][b0 + cc] = tv[ii];
                }
            }
            __syncthreads();
            for (int idx = tid; idx < nrows * nrows; idx += 256) {
                int r = b0 + 16 + idx / nrows, cc = b0 + 16 + idx % nrows;
                if (cc <= r) {
                    double acc = 0.0;
#pragma unroll
                    for (int t = 0; t < 16; ++t)
                        acc = fma(sA[r][b0 + t], sA[cc][b0 + t], acc);
                    sA[r][cc] -= acc;
                }
            }
            __syncthreads();
        }
    }
    // assemble off-diagonal 16x16 blocks of X = inv(L64): 3 levels
    for (int d = 1; d <= 3; ++d) {
        __syncthreads();
        int npairs = 4 - d;
        for (int i2 = tid; i2 < npairs * 256; i2 += 256) {
            int pr = i2 >> 8, cell = i2 & 255, r = cell >> 4, c = cell & 15;
            int qc = pr, qr = pr + d;
            double w = 0.0;
            for (int t = 16 * qc; t < 16 * qr; ++t)
                w = fma(sA[16 * qr + r][t], sX[t][16 * qc + c], w);
            sW[pr * 272 + r * 17 + c] = w;
        }
        __syncthreads();
        for (int i2 = tid; i2 < npairs * 256; i2 += 256) {
            int pr = i2 >> 8, cell = i2 & 255, r = cell >> 4, c = cell & 15;
            int qc = pr, qr = pr + d;
            double x2 = 0.0;
            for (int t = 0; t <= r; ++t)
                x2 = fma(sX[16 * qr + r][16 * qr + t], sW[pr * 272 + t * 17 + c], x2);
            sX[16 * qr + r][16 * qc + c] = -x2;
        }
    }
    __syncthreads();
    for (int idx = tid; idx < 4096; idx += 256) {
        int r = idx >> 6, c = idx & 63;
        double xv = sX[r][c];
        Dinv[(size_t)p * 4096 + idx] = xv;
        DinvT[(size_t)p * 4096 + (size_t)c * 64 + r] = xv;
        W[(size_t)(k0 + r) * 512 + k0 + c] = xv;   // W diag tile (upper zeros)
    }
    __syncthreads();
}

// factor of panel 0 (separate tiny launch)
__global__ __launch_bounds__(256) void factor0_kernel(const double* __restrict__ A,
                                                      double* __restrict__ W,
                                                      double* __restrict__ Dinv,
                                                      double* __restrict__ DinvT) {
    __shared__ double smem[2 * 64 * 65 + 816];
    double (*sA)[65] = (double(*)[65])smem;
    double (*sX)[65] = (double(*)[65])(smem + 64 * 65);
    double* sW = smem + 2 * 64 * 65;
    const int tid = threadIdx.x;
    for (int idx = tid; idx < 4096; idx += 256) {
        int r = idx >> 6, c = idx & 63;
        sA[r][c] = (c <= r) ? A[(size_t)r * 512 + c] : 0.0;
    }
    factor64(sA, sX, sW, W, Dinv, DinvT, 0);  // leading barrier covers load
}

// ---------------------------------------------------------------------------
// trailing-update tile for panel p: recompute L_Ip, L_Jp from A and DinvT;
// diag blocks write L_Ip to LT; update A_IJ; block (0,0) factors panel p+1.
// ---------------------------------------------------------------------------
__device__ void upd_tile(double* smem, double* __restrict__ A, double* __restrict__ LT,
                         double* __restrict__ W, double* __restrict__ Dinv,
                         double* __restrict__ DinvT, int p, int s) {
    double (*sLi)[67] = (double(*)[67])smem;
    double (*sLj)[67] = (double(*)[67])(smem + 64 * 67);
    double (*sD)[64]  = (double(*)[64])(smem + 2 * 64 * 67);
    int bi = 0;
    while (s >= bi + 1) { s -= bi + 1; ++bi; }
    const int bj = s;
    const int I = p + 1 + bi, J = p + 1 + bj;
    const bool diag = (I == J);
    const int tid = threadIdx.x;
    const int tx = tid & 15, ty = tid >> 4;

    const double* Ati = A + (size_t)I * 64 * 512 + (size_t)p * 64;
    const double* Atj = A + (size_t)J * 64 * 512 + (size_t)p * 64;
    for (int idx = tid; idx < 4096; idx += 256) {
        int r = idx >> 6, c = idx & 63;
        sLi[r][c] = Ati[(size_t)r * 512 + c];
        if (!diag) sLj[r][c] = Atj[(size_t)r * 512 + c];
        sD[r][c] = DinvT[(size_t)p * 4096 + idx];
    }
    __syncthreads();

    double lip[4][4] = {}, ljp[4][4] = {};
    for (int t = 0; t < 64; ++t) {
        double b0 = sD[t][4 * tx + 0], b1 = sD[t][4 * tx + 1];
        double b2 = sD[t][4 * tx + 2], b3 = sD[t][4 * tx + 3];
#pragma unroll
        for (int r = 0; r < 4; ++r) {
            double a = sLi[4 * ty + r][t];
            lip[r][0] = fma(a, b0, lip[r][0]);
            lip[r][1] = fma(a, b1, lip[r][1]);
            lip[r][2] = fma(a, b2, lip[r][2]);
            lip[r][3] = fma(a, b3, lip[r][3]);
        }
        if (!diag) {
#pragma unroll
            for (int r = 0; r < 4; ++r) {
                double a = sLj[4 * ty + r][t];
                ljp[r][0] = fma(a, b0, ljp[r][0]);
                ljp[r][1] = fma(a, b1, ljp[r][1]);
                ljp[r][2] = fma(a, b2, ljp[r][2]);
                ljp[r][3] = fma(a, b3, ljp[r][3]);
            }
        }
    }
    __syncthreads();
#pragma unroll
    for (int r = 0; r < 4; ++r)
#pragma unroll
        for (int c = 0; c < 4; ++c) {
            sLi[4 * ty + r][4 * tx + c] = lip[r][c];
            if (!diag) sLj[4 * ty + r][4 * tx + c] = ljp[r][c];
        }
    if (diag) {   // publish L column-panel p tile (I,p) to LT
#pragma unroll
        for (int r = 0; r < 4; ++r)
#pragma unroll
            for (int c = 0; c < 4; ++c)
                LT[(size_t)(p * 64 + 4 * tx + c) * 512 + (size_t)I * 64 + 4 * ty + r] = lip[r][c];
    }
    __syncthreads();

    double (*Bp)[67] = diag ? sLi : sLj;
    double acc[4][4] = {};
    for (int t = 0; t < 64; ++t) {
        double a0 = sLi[4 * ty + 0][t], a1 = sLi[4 * ty + 1][t];
        double a2 = sLi[4 * ty + 2][t], a3 = sLi[4 * ty + 3][t];
        double b0 = Bp[4 * tx + 0][t], b1 = Bp[4 * tx + 1][t];
        double b2 = Bp[4 * tx + 2][t], b3 = Bp[4 * tx + 3][t];
        acc[0][0] = fma(a0, b0, acc[0][0]); acc[0][1] = fma(a0, b1, acc[0][1]);
        acc[0][2] = fma(a0, b2, acc[0][2]); acc[0][3] = fma(a0, b3, acc[0][3]);
        acc[1][0] = fma(a1, b0, acc[1][0]); acc[1][1] = fma(a1, b1, acc[1][1]);
        acc[1][2] = fma(a1, b2, acc[1][2]); acc[1][3] = fma(a1, b3, acc[1][3]);
        acc[2][0] = fma(a2, b0, acc[2][0]); acc[2][1] = fma(a2, b1, acc[2][1]);
        acc[2][2] = fma(a2, b2, acc[2][2]); acc[2][3] = fma(a2, b3, acc[2][3]);
        acc[3][0] = fma(a3, b0, acc[3][0]); acc[3][1] = fma(a3, b1, acc[3][1]);
        acc[3][2] = fma(a3, b2, acc[3][2]); acc[3][3] = fma(a3, b3, acc[3][3]);
    }

    double* Aij = A + (size_t)I * 64 * 512 + (size_t)J * 64;
    if (bi == 0 && bj == 0) {
        __syncthreads();
        double (*fA)[65] = (double(*)[65])smem;
        double (*fX)[65] = (double(*)[65])(smem + 64 * 65);
        double* fW = smem + 2 * 64 * 65;
#pragma unroll
        for (int r = 0; r < 4; ++r)
#pragma unroll
            for (int c = 0; c < 4; ++c) {
                int rr = 4 * ty + r, cc = 4 * tx + c;
                fA[rr][cc] = (cc <= rr) ? (Aij[(size_t)rr * 512 + cc] - acc[r][c]) : 0.0;
            }
        __syncthreads();
        factor64(fA, fX, fW, W, Dinv, DinvT, p + 1);
    } else {
#pragma unroll
        for (int r = 0; r < 4; ++r)
#pragma unroll
            for (int c = 0; c < 4; ++c) {
                int rr = 4 * ty + r, cc = 4 * tx + c;
                if (!diag || cc <= rr)
                    Aij[(size_t)rr * 512 + cc] -= acc[r][c];
            }
        __syncthreads();
    }
}

// ---------------------------------------------------------------------------
// W row-panel p, tile J (J<p): X_pJ = -Dinv_p * sum_{K=J..p-1} L_pK * X_KJ
// ---------------------------------------------------------------------------
__device__ void wrow_tile(double* smem, const double* __restrict__ LT,
                          double* __restrict__ W, const double* __restrict__ Dinv,
                          int p, int J) {
    double (*Lk)[65] = (double(*)[65])smem;
    double (*Xk)[65] = (double(*)[65])(smem + 64 * 65);
    double (*Sd)[65] = (double(*)[65])(smem + 2 * 64 * 65);
    const int tid = threadIdx.x;
    const int tx = tid & 15, ty = tid >> 4;
    double S[4][4] = {};
    for (int K = J; K < p; ++K) {
        for (int idx = tid; idx < 4096; idx += 256) {
            int t = idx >> 6, r = idx & 63;
            Lk[t][r] = LT[(size_t)(K * 64 + t) * 512 + p * 64 + r];   // = L_pK[r][t]
            Xk[t][r] = W[(size_t)(K * 64 + t) * 512 + J * 64 + r];    // = X_KJ[t][r]
        }
        __syncthreads();
        for (int t = 0; t < 64; ++t) {
            double x0 = Xk[t][4 * tx + 0], x1 = Xk[t][4 * tx + 1];
            double x2 = Xk[t][4 * tx + 2], x3 = Xk[t][4 * tx + 3];
#pragma unroll
            for (int r = 0; r < 4; ++r) {
                double l = Lk[t][4 * ty + r];
                S[r][0] = fma(l, x0, S[r][0]);
                S[r][1] = fma(l, x1, S[r][1]);
                S[r][2] = fma(l, x2, S[r][2]);
                S[r][3] = fma(l, x3, S[r][3]);
            }
        }
        __syncthreads();
    }
#pragma unroll
    for (int r = 0; r < 4; ++r)
#pragma unroll
        for (int c = 0; c < 4; ++c)
            Sd[4 * ty + r][4 * tx + c] = S[r][c];
    for (int idx = tid; idx < 4096; idx += 256) {
        int r = idx >> 6, t = idx & 63;
        Lk[r][t] = Dinv[(size_t)p * 4096 + idx];   // Dp[r][t]
    }
    __syncthreads();
    double X[4][4] = {};
    for (int t = 0; t < 64; ++t) {
        double s0 = Sd[t][4 * tx + 0], s1 = Sd[t][4 * tx + 1];
        double s2 = Sd[t][4 * tx + 2], s3 = Sd[t][4 * tx + 3];
#pragma unroll
        for (int r = 0; r < 4; ++r) {
            double d = Lk[4 * ty + r][t];
            X[r][0] = fma(d, s0, X[r][0]);
            X[r][1] = fma(d, s1, X[r][1]);
            X[r][2] = fma(d, s2, X[r][2]);
            X[r][3] = fma(d, s3, X[r][3]);
        }
    }
#pragma unroll
    for (int r = 0; r < 4; ++r)
#pragma unroll
        for (int c = 0; c < 4; ++c)
            W[(size_t)(p * 64 + 4 * ty + r) * 512 + J * 64 + 4 * tx + c] = -X[r][c];
}

// upd launch p: blocks [0,nupd) trailing tiles; [nupd, nupd+p) W row-panel p
__global__ __launch_bounds__(256) void upd_kernel(double* __restrict__ A,
                                                  double* __restrict__ LT,
                                                  double* __restrict__ W,
                                                  double* __restrict__ Dinv,
                                                  double* __restrict__ DinvT,
                                                  int p) {
    __shared__ double smem[2 * 64 * 67 + 64 * 64];
    const int nupd = (7 - p) * (8 - p) / 2;
    if ((int)blockIdx.x < nupd)
        upd_tile(smem, A, LT, W, Dinv, DinvT, p, blockIdx.x);
    else
        wrow_tile(smem, LT, W, Dinv, p, blockIdx.x - nupd);
}

__global__ __launch_bounds__(256) void wrow7_kernel(const double* __restrict__ LT,
                                                    double* __restrict__ W,
                                                    const double* __restrict__ Dinv) {
    __shared__ double smem[3 * 64 * 65];
    wrow_tile(smem, LT, W, Dinv, 7, blockIdx.x);
}

// ---------------------------------------------------------------------------
// GEMMs: T = W*B, then Z = W^T*T. B,T,Z col-major [col][512].
// ---------------------------------------------------------------------------
__global__ __launch_bounds__(256) void gemm1_kernel(const double* __restrict__ W,
                                                    const double* __restrict__ Bc,
                                                    double* __restrict__ Tbuf) {
    __shared__ double smem[2 * 64 * 65];
    const int blk = blockIdx.x;
    const int i = blk / 5, ct = blk % 5;
    const int c0 = ct * 64;
    const int ncols = (257 - c0 < 64) ? (257 - c0) : 64;
    double (*Wt)[65] = (double(*)[65])smem;
    double (*Bs)[65] = (double(*)[65])(smem + 64 * 65);
    const int tid = threadIdx.x;
    const int tx = tid & 15, ty = tid >> 4;
    double acc[4][4] = {};
    for (int j = 0; j <= i; ++j) {
        for (int idx = tid; idx < 4096; idx += 256) {
            int r = idx >> 6, c = idx & 63;
            Wt[r][c] = W[(size_t)(i * 64 + r) * 512 + j * 64 + c];
            Bs[r][c] = (r < ncols) ? Bc[(size_t)(c0 + r) * 512 + j * 64 + c] : 0.0;
        }
        __syncthreads();
        for (int t = 0; t < 64; ++t) {
            double b0 = Bs[4 * tx + 0][t], b1 = Bs[4 * tx + 1][t];
            double b2 = Bs[4 * tx + 2][t], b3 = Bs[4 * tx + 3][t];
#pragma unroll
            for (int r = 0; r < 4; ++r) {
                double w = Wt[4 * ty + r][t];
                acc[r][0] = fma(w, b0, acc[r][0]);
                acc[r][1] = fma(w, b1, acc[r][1]);
                acc[r][2] = fma(w, b2, acc[r][2]);
                acc[r][3] = fma(w, b3, acc[r][3]);
            }
        }
        __syncthreads();
    }
#pragma unroll
    for (int r = 0; r < 4; ++r)
#pragma unroll
        for (int c = 0; c < 4; ++c)
            if (4 * tx + c < ncols)
                Tbuf[(size_t)(c0 + 4 * tx + c) * 512 + i * 64 + 4 * ty + r] = acc[r][c];
}

__global__ __launch_bounds__(256) void gemm2_kernel(const double* __restrict__ W,
                                                    const double* __restrict__ Tbuf,
                                                    double* __restrict__ Bc) {
    __shared__ double smem[2 * 64 * 65];
    const int blk = blockIdx.x;
    const int i = blk / 5, ct = blk % 5;
    const int c0 = ct * 64;
    const int ncols = (257 - c0 < 64) ? (257 - c0) : 64;
    double (*Wt)[65] = (double(*)[65])smem;
    double (*Ts)[65] = (double(*)[65])(smem + 64 * 65);
    const int tid = threadIdx.x;
    const int tx = tid & 15, ty = tid >> 4;
    double acc[4][4] = {};
    for (int j = i; j < 8; ++j) {
        for (int idx = tid; idx < 4096; idx += 256) {
            int r = idx >> 6, c = idx & 63;
            Wt[r][c] = W[(size_t)(j * 64 + r) * 512 + i * 64 + c];
            Ts[r][c] = (r < ncols) ? Tbuf[(size_t)(c0 + r) * 512 + j * 64 + c] : 0.0;
        }
        __syncthreads();
        for (int t = 0; t < 64; ++t) {
            double t0 = Ts[4 * tx + 0][t], t1 = Ts[4 * tx + 1][t];
            double t2 = Ts[4 * tx + 2][t], t3 = Ts[4 * tx + 3][t];
#pragma unroll
            for (int r = 0; r < 4; ++r) {
                double w = Wt[t][4 * ty + r];   // (W_ji)^T[r][t]
                acc[r][0] = fma(w, t0, acc[r][0]);
                acc[r][1] = fma(w, t1, acc[r][1]);
                acc[r][2] = fma(w, t2, acc[r][2]);
                acc[r][3] = fma(w, t3, acc[r][3]);
            }
        }
        __syncthreads();
    }
#pragma unroll
    for (int r = 0; r < 4; ++r)
#pragma unroll
        for (int c = 0; c < 4; ++c)
            if (4 * tx + c < ncols)
                Bc[(size_t)(c0 + 4 * tx + c) * 512 + i * 64 + 4 * ty + r] = acc[r][c];
}

// column reductions over Z (col-major [257][512]); 4 cols per block
__global__ __launch_bounds__(256) void colreduce_kernel(const double* __restrict__ Z,
                                                        const float* __restrict__ ys,
                                                        const float* __restrict__ b_p,
                                                        float* __restrict__ out,
                                                        double* __restrict__ kbx,
                                                        double* __restrict__ Sp) {
    const int lane = threadIdx.x & 63, w = threadIdx.x >> 6;
    const int c = blockIdx.x * 4 + w;
    if (c >= 257) return;
    const double b = (double)b_p[0];
    double s0 = 0.0, s1 = 0.0;
#pragma unroll
    for (int t = 0; t < 8; ++t) {
        int n = lane + 64 * t;
        double zv = Z[(size_t)c * 512 + n];
        s0 += zv;
        s1 = fma(zv, (double)ys[n] - b, s1);
    }
#pragma unroll
    for (int off = 1; off < 64; off <<= 1) {
        s0 += __shfl_xor(s0, off, 64);
        s1 += __shfl_xor(s1, off, 64);
    }
    if (lane == 0) {
        if (c < 256) { out[c] = (float)(b + s1); kbx[c] = s0; }
        else Sp[0] = s0;
    }
}

// cov[i][j] = Kxx[i][j] - sum_n Z[i][n]*Kox[n][j] + (1-kbx[i])(1-kbx[j])/S
__global__ __launch_bounds__(256) void cov_kernel(const double* __restrict__ Z,
                                                  const float* __restrict__ Kox,
                                                  const float* __restrict__ Kxx,
                                                  const double* __restrict__ kbx,
                                                  const double* __restrict__ Sp,
                                                  float* __restrict__ out) {
    const int bj = blockIdx.x, bi = blockIdx.y;
    const int tx = threadIdx.x & 15, ty = threadIdx.x >> 4;
    const int i = bi * 16 + ty, j = bj * 16 + tx;
    __shared__ double sZ[16][17];
    __shared__ float sK[16][17];
    double acc = 0.0;
    for (int kt = 0; kt < 32; ++kt) {
        sZ[ty][tx] = Z[(size_t)i * 512 + kt * 16 + tx];
        sK[ty][tx] = Kox[(size_t)(kt * 16 + ty) * 256 + j];
        __syncthreads();
#pragma unroll
        for (int t = 0; t < 16; ++t) acc = fma(sZ[ty][t], (double)sK[t][tx], acc);
        __syncthreads();
    }
    const double S = Sp[0];
    const double corr = (1.0 - kbx[i]) * (1.0 - kbx[j]) / S;
    out[(size_t)(1 + i) * 256 + j] = (float)((double)Kxx[(size_t)i * 256 + j] - acc + corr);
}

// ---------------------------------------------------------------------------
extern "C" void kernel_launch(void* const* d_in, const int* in_sizes, int n_in,
                              void* d_out, int out_size, void* d_ws, size_t ws_size,
                              hipStream_t stream) {
    const float* X_test = (const float*)d_in[0];
    const float* A_test = (const float*)d_in[1];
    const float* X_obs  = (const float*)d_in[2];
    const float* A_obs  = (const float*)d_in[3];
    const float* ys     = (const float*)d_in[4];
    const float* rho_p  = (const float*)d_in[5];
    const float* g_p    = (const float*)d_in[6];
    const float* nu_p   = (const float*)d_in[7];
    const float* b_p    = (const float*)d_in[8];
    float* out = (float*)d_out;
    char* ws = (char*)d_ws;

    double* Koo  = (double*)(ws + 0);         // 2,097,152 (A, in-place updates)
    double* LT   = (double*)(ws + 2097152);   // 2,097,152 (L col-panels, transposed)
    double* Bc   = (double*)(ws + 4194304);   // 1,052,672 (RHS -> Z)
    float*  Kox  = (float*) (ws + 5246976);   // 524,288
    float*  Kxx  = (float*) (ws + 5771264);   // 262,144
    float*  s1v  = (float*) (ws + 6033408);   // 1,024
    float*  s2v  = (float*) (ws + 6034432);   // 2,048
    double* kbx  = (double*)(ws + 6036480);   // 2,048
    double* Sp   = (double*)(ws + 6038528);   // 1,024 pad
    double* Dinv = (double*)(ws + 6039552);   // 262,144
    double* DinvT= (double*)(ws + 6301696);   // 262,144
    double* W    = (double*)(ws + 6563840);   // 2,097,152 (inv(L), lower)
    double* Tbuf = (double*)(ws + 8660992);   // 1,052,672 (end 9,713,664)
    float*  atT  = (float*)(ws + 2097152);           // in LT space (pre-chol)
    float*  atO  = (float*)(ws + 2097152 + 24576);

    self_kernel<<<M + N + 1, 64, 0, stream>>>(X_test, A_test, X_obs, A_obs,
                                              s1v, s2v, atT, atO, Bc);

    gram_kernel<<<dim3(32, 64, 3), 128, 0, stream>>>(X_test, atT, s1v,
                                                     X_obs, atO, s2v,
                                                     rho_p, nu_p, g_p,
                                                     Kox, Kxx, Koo, Bc);

    factor0_kernel<<<1, 256, 0, stream>>>(Koo, W, Dinv, DinvT);
    for (int p = 0; p < 7; ++p) {
        int nb = (7 - p) * (8 - p) / 2 + p;   // trailing tiles + W row-panel p
        upd_kernel<<<nb, 256, 0, stream>>>(Koo, LT, W, Dinv, DinvT, p);
    }
    wrow7_kernel<<<7, 256, 0, stream>>>(LT, W, Dinv);

    gemm1_kernel<<<40, 256, 0, stream>>>(W, Bc, Tbuf);
    gemm2_kernel<<<40, 256, 0, stream>>>(W, Tbuf, Bc);
    colreduce_kernel<<<65, 256, 0, stream>>>(Bc, ys, b_p, out, kbx, Sp);

    cov_kernel<<<dim3(16, 16), 256, 0, stream>>>(Bc, Kox, Kxx, kbx, Sp, out);
}

// Round 12
// 975.329 us; speedup vs baseline: 1.2176x; 1.2176x over previous
//
#include <hip/hip_runtime.h>
#include <cmath>

// Problem constants
#define M 256
#define N 512
#define P 24
#define D 8

// ---------------------------------------------------------------------------
// self terms + folded weights at[i,u] = A[i,u]*exp(-0.5*||x_iu||^2).
// Block M+N writes the ones-column of Bc.
// ---------------------------------------------------------------------------
__global__ __launch_bounds__(64) void self_kernel(const float* __restrict__ X_test,
                                                  const float* __restrict__ A_test,
                                                  const float* __restrict__ X_obs,
                                                  const float* __restrict__ A_obs,
                                                  float* __restrict__ s1,
                                                  float* __restrict__ s2,
                                                  float* __restrict__ atT,
                                                  float* __restrict__ atO,
                                                  double* __restrict__ Bc) {
    const int bid = blockIdx.x;
    const int lane = threadIdx.x;
    if (bid == M + N) {  // ones column (col 256 of Bc, col-major [257][512])
#pragma unroll
        for (int t = 0; t < 8; ++t) Bc[(size_t)256 * 512 + 64 * t + lane] = 1.0;
        return;
    }
    const float* X; const float* A; float* s; float* at; int i;
    if (bid < M) { X = X_test; A = A_test; s = s1; at = atT; i = bid; }
    else         { X = X_obs;  A = A_obs;  s = s2; at = atO; i = bid - M; }
    const float* Xi = X + (size_t)i * P * D;
    const float* Ai = A + (size_t)i * P;
    float acc = 0.f;
#pragma unroll
    for (int t = 0; t < 9; ++t) {
        int idx = lane + 64 * t;          // 0..575
        int u = idx / 24;
        int v = idx - u * 24;
        const float* xu = Xi + u * D;
        const float* xv = Xi + v * D;
        float d2 = 0.f;
#pragma unroll
        for (int d = 0; d < D; ++d) { float df = xu[d] - xv[d]; d2 = fmaf(df, df, d2); }
        acc = fmaf(Ai[u] * Ai[v], __expf(-0.5f * d2), acc);
    }
#pragma unroll
    for (int off = 1; off < 64; off <<= 1) acc += __shfl_xor(acc, off, 64);
    if (lane == 0) s[i] = acc;
    if (lane < 24) {
        const float* xp = Xi + lane * D;
        float q = 0.f;
#pragma unroll
        for (int d = 0; d < D; ++d) q = fmaf(xp[d], xp[d], q);
        at[(size_t)i * P + lane] = Ai[lane] * __expf(-0.5f * q);
    }
}

// ---------------------------------------------------------------------------
// fused gram kernel with norm-folded weights. mode1 writes KoxT (f32,
// [test j][obs i], coalesced) and Bc.
// ---------------------------------------------------------------------------
__global__ __launch_bounds__(128) void gram_kernel(
    const float* __restrict__ Xt, const float* __restrict__ atT, const float* __restrict__ s1,
    const float* __restrict__ Xo, const float* __restrict__ atO, const float* __restrict__ s2,
    const float* __restrict__ rho_p, const float* __restrict__ nu_p, const float* __restrict__ g_p,
    float* __restrict__ KoxT, float* __restrict__ Kxx, double* __restrict__ Koo,
    double* __restrict__ Bc) {
    const int mode = blockIdx.z;
    const int it = blockIdx.x, jt = blockIdx.y;
    const float *X1, *AT1, *S1, *X2, *AT2, *S2;
    if (mode == 0) {
        if (jt > 2 * it + 1) return;
        X1 = Xo; AT1 = atO; S1 = s2; X2 = Xo; AT2 = atO; S2 = s2;
    } else if (mode == 1) {
        if (jt >= 32) return;
        X1 = Xo; AT1 = atO; S1 = s2; X2 = Xt; AT2 = atT; S2 = s1;
    } else {
        if (it >= 16 || jt >= 32 || jt < 2 * it) return;
        X1 = Xt; AT1 = atT; S1 = s1; X2 = Xt; AT2 = atT; S2 = s1;
    }
    const int i0 = it * 16, j0 = jt * 8;
    const int tid = threadIdx.x;
    const int il = tid >> 3, uc = tid & 7;
    const int i = i0 + il;

    __shared__ __align__(16) float X2s[8 * 192];
    __shared__ float A2s[8 * 24];
    __shared__ float S2s[8];
    {
        const float4* gx = (const float4*)(X2 + (size_t)j0 * 192);
        float4* lx = (float4*)X2s;
        for (int idx = tid; idx < 8 * 48; idx += 128) lx[idx] = gx[idx];
        for (int idx = tid; idx < 8 * 24; idx += 128) A2s[idx] = AT2[(size_t)j0 * 24 + idx];
        if (tid < 8) S2s[tid] = S2[j0 + tid];
    }
    __syncthreads();

    float x1r[3][8], at1r[3];
#pragma unroll
    for (int ss = 0; ss < 3; ++ss) {
        const float* p = X1 + ((size_t)i * P + uc * 3 + ss) * D;
#pragma unroll
        for (int d = 0; d < D; ++d) x1r[ss][d] = p[d];
        at1r[ss] = AT1[(size_t)i * P + uc * 3 + ss];
    }
    const float s1i = S1[i];
    const float rho = rho_p[0], nu = nu_p[0], g = g_p[0];

    for (int jj = 0; jj < 8; ++jj) {
        const float* xb = X2s + jj * 192;
        float e0 = 0.f, e1 = 0.f, e2 = 0.f;
#pragma unroll 4
        for (int v = 0; v < 24; ++v) {
            const float4 q0 = ((const float4*)(xb + v * 8))[0];
            const float4 q1 = ((const float4*)(xb + v * 8))[1];
            float x2r[8];
            x2r[0] = q0.x; x2r[1] = q0.y; x2r[2] = q0.z; x2r[3] = q0.w;
            x2r[4] = q1.x; x2r[5] = q1.y; x2r[6] = q1.z; x2r[7] = q1.w;
            const float w2 = A2s[jj * 24 + v];
            float d0 = 0.f, d1 = 0.f, d2 = 0.f;
#pragma unroll
            for (int dd = 0; dd < 8; ++dd) {
                d0 = fmaf(x1r[0][dd], x2r[dd], d0);
                d1 = fmaf(x1r[1][dd], x2r[dd], d1);
                d2 = fmaf(x1r[2][dd], x2r[dd], d2);
            }
            e0 = fmaf(w2, __expf(d0), e0);
            e1 = fmaf(w2, __expf(d1), e1);
            e2 = fmaf(w2, __expf(d2), e2);
        }
        float acc = at1r[0] * e0;
        acc = fmaf(at1r[1], e1, acc);
        acc = fmaf(at1r[2], e2, acc);
        acc += __shfl_xor(acc, 1, 8);
        acc += __shfl_xor(acc, 2, 8);
        acc += __shfl_xor(acc, 4, 8);
        if (uc == 0) {
            const int j = j0 + jj;
            float d2p = fmaxf(s1i + S2s[jj] - 2.f * acc, 0.f);
            float kv = __expf(-0.5f * d2p / rho);
            if (mode == 0) {
                if (j <= i) Koo[(size_t)i * 512 + j] = (double)(nu * (kv + ((i == j) ? g : 0.f)));
            } else if (mode == 1) {
                float val = nu * kv;
                KoxT[(size_t)j * 512 + i] = val;
                Bc[(size_t)j * 512 + i] = (double)val;
            } else {
                float val = nu * kv;
                if (j >= i) {
                    Kxx[(size_t)i * 256 + j] = val;
                    if (j > i) Kxx[(size_t)j * 256 + i] = val;
                }
            }
        }
    }
}

// ---------------------------------------------------------------------------
// Conflict-free 64x64 f64 tile engine (r11). LDS tile = 4096 doubles,
// row-major, 16B pair-blocks XOR-swizzled by (row>>2).
// ---------------------------------------------------------------------------
__device__ __forceinline__ double2 ld2t(const double* T, int r, int m) {
    return *(const double2*)(T + r * 64 + 2 * ((m ^ (r >> 2)) & 31));
}
__device__ __forceinline__ void st2t(double* T, int r, int m, double x, double y) {
    double2 v; v.x = x; v.y = y;
    *(double2*)(T + r * 64 + 2 * ((m ^ (r >> 2)) & 31)) = v;
}

__device__ void stage_tile(double* T, const double* G, int ldg, int nrows) {
    const int tid = threadIdx.x;
#pragma unroll
    for (int e = 0; e < 8; ++e) {
        int idx = tid + 256 * e, r = idx >> 5, m = idx & 31;
        double x = 0.0, y = 0.0;
        if (r < nrows) {
            double2 v = *(const double2*)(G + (size_t)r * ldg + 2 * m);
            x = v.x; y = v.y;
        }
        st2t(T, r, m, x, y);
    }
}
__device__ void stage_tile_f(double* T, const float* G, int ldg) {
    const int tid = threadIdx.x;
#pragma unroll
    for (int e = 0; e < 8; ++e) {
        int idx = tid + 256 * e, r = idx >> 5, m = idx & 31;
        float2 v = *(const float2*)(G + (size_t)r * ldg + 2 * m);
        st2t(T, r, m, (double)v.x, (double)v.y);
    }
}

// acc[r][c] += sum_t At[4ty+r][t] * Bt[4tx+c][t]
__device__ __forceinline__ void mac4x4(const double* At, const double* Bt,
                                       double acc[4][4], int tx, int ty) {
#pragma unroll 4
    for (int m = 0; m < 32; ++m) {
        double2 a[4], b[4];
#pragma unroll
        for (int j = 0; j < 4; ++j) a[j] = ld2t(At, 4 * ty + j, m);
#pragma unroll
        for (int j = 0; j < 4; ++j) b[j] = ld2t(Bt, 4 * tx + j, m);
#pragma unroll
        for (int r = 0; r < 4; ++r)
#pragma unroll
            for (int c = 0; c < 4; ++c)
                acc[r][c] = fma(a[r].y, b[c].y, fma(a[r].x, b[c].x, acc[r][c]));
    }
}

__device__ void stt_tile(double* T, const double v[4][4], int tx, int ty) {
#pragma unroll
    for (int r = 0; r < 4; ++r)
#pragma unroll
        for (int mp = 0; mp < 2; ++mp)
            st2t(T, 4 * ty + r, 2 * tx + mp, v[r][2 * mp], v[r][2 * mp + 1]);
}

#define LO(i, j) ((i) * ((i) + 1) / 2 + (j))   // packed lower-tile index (i>=j)

// ---------------------------------------------------------------------------
// factor64 (register 16x16 Cholesky+inverse, verified r10) -> packed Wp/WTp
// diag tile p = inv(L_pp).
// ---------------------------------------------------------------------------
__device__ void factor64(double (*sA)[65], double (*sX)[65], double* sW,
                         double* Wp, double* WTp, int p) {
    const int tid = threadIdx.x;
    {
        double* f = &sX[0][0];
        for (int idx = tid; idx < 64 * 65; idx += 256) f[idx] = 0.0;
    }
    __syncthreads();
    for (int q = 0; q < 4; ++q) {
        const int b0 = 16 * q;
        if (tid < 64) {
            const int rr = tid >> 2, gg = tid & 3;
            double a[4], x[4];
#pragma unroll
            for (int j = 0; j < 4; ++j) {
                int cc = 4 * gg + j;
                a[j] = (cc <= rr) ? sA[b0 + rr][b0 + cc] : sA[b0 + cc][b0 + rr];
                x[j] = 0.0;
            }
#pragma unroll
            for (int k = 0; k < 16; ++k) {
                double akk = __shfl(a[k & 3], (k << 2) | (k >> 2), 64);
                double rd = 1.0 / sqrt(akk);
                if (gg == (k >> 2) && rr >= k)
                    a[k & 3] = (rr == k) ? akk * rd : a[k & 3] * rd;
                if (k < 15) {
                    double lrk = __shfl(a[k & 3], (rr << 2) | (k >> 2), 64);
                    double lck[4];
#pragma unroll
                    for (int j = 0; j < 4; ++j)
                        lck[j] = __shfl(a[k & 3], ((4 * gg + j) << 2) | (k >> 2), 64);
#pragma unroll
                    for (int j = 0; j < 4; ++j) {
                        int cc = 4 * gg + j;
                        if (rr > k && cc > k) a[j] = fma(-lrk, lck[j], a[j]);
                    }
                }
            }
#pragma unroll
            for (int r2 = 0; r2 < 16; ++r2) {
                double s0 = 0.0, s1 = 0.0, s2 = 0.0, s3 = 0.0;
#pragma unroll
                for (int t = 0; t < r2; ++t) {
                    double lrt = __shfl(a[t & 3], (r2 << 2) | (t >> 2), 64);
                    s0 = fma(lrt, __shfl(x[0], (t << 2) | gg, 64), s0);
                    s1 = fma(lrt, __shfl(x[1], (t << 2) | gg, 64), s1);
                    s2 = fma(lrt, __shfl(x[2], (t << 2) | gg, 64), s2);
                    s3 = fma(lrt, __shfl(x[3], (t << 2) | gg, 64), s3);
                }
                double lrr = __shfl(a[r2 & 3], (r2 << 2) | (r2 >> 2), 64);
                double rdr = 1.0 / lrr;
                if (rr == r2) {
                    double sv[4] = {s0, s1, s2, s3};
#pragma unroll
                    for (int j = 0; j < 4; ++j) {
                        int cc = 4 * gg + j;
                        x[j] = (cc <= r2) ? (((cc == r2) ? 1.0 : 0.0) - sv[j]) * rdr : 0.0;
                    }
                }
            }
#pragma unroll
            for (int j = 0; j < 4; ++j) {
                int cc = 4 * gg + j;
                if (cc <= rr) sA[b0 + rr][b0 + cc] = a[j];
                sX[b0 + rr][b0 + cc] = x[j];
            }
        }
        __syncthreads();
        if (q < 3) {
            const int nrows = 48 - b0;
            const int cells = nrows * 16;
            double tv[3];
#pragma unroll
            for (int ii = 0; ii < 3; ++ii) {
                int idx = tid + 256 * ii;
                tv[ii] = 0.0;
                if (idx < cells) {
                    int a2 = b0 + 16 + (idx >> 4), cc = idx & 15;
                    double acc = 0.0;
                    for (int t = 0; t <= cc; ++t)
                        acc = fma(sA[a2][b0 + t], sX[b0 + cc][b0 + t], acc);
                    tv[ii] = acc;
                }
            }
            __syncthreads();
#pragma unroll
            for (int ii = 0; ii < 3; ++ii) {
                int idx = tid + 256 * ii;
                if (idx < cells) {
                    int a2 = b0 + 16 + (idx >> 4), cc = idx & 15;
                    sA[a2][b0 + cc] = tv[ii];
                }
            }
            __syncthreads();
            for (int idx = tid; idx < nrows * nrows; idx += 256) {
                int r = b0 + 16 + idx / nrows, cc = b0 + 16 + idx % nrows;
                if (cc <= r) {
                    double acc = 0.0;
#pragma unroll
                    for (int t = 0; t < 16; ++t)
                        acc = fma(sA[r][b0 + t], sA[cc][b0 + t], acc);
                    sA[r][cc] -= acc;
                }
            }
            __syncthreads();
        }
    }
    for (int d = 1; d <= 3; ++d) {
        __syncthreads();
        int npairs = 4 - d;
        for (int i2 = tid; i2 < npairs * 256; i2 += 256) {
            int pr = i2 >> 8, cell = i2 & 255, r = cell >> 4, c = cell & 15;
            int qc = pr, qr = pr + d;
            double w = 0.0;
            for (int t = 16 * qc; t < 16 * qr; ++t)
                w = fma(sA[16 * qr + r][t], sX[t][16 * qc + c], w);
            sW[pr * 272 + r * 17 + c] = w;
        }
        __syncthreads();
        for (int i2 = tid; i2 < npairs * 256; i2 += 256) {
            int pr = i2 >> 8, cell = i2 & 255, r = cell >> 4, c = cell & 15;
            int qc = pr, qr = pr + d;
            double x2 = 0.0;
            for (int t = 0; t <= r; ++t)
                x2 = fma(sX[16 * qr + r][16 * qr + t], sW[pr * 272 + t * 17 + c], x2);
            sX[16 * qr + r][16 * qc + c] = -x2;
        }
    }
    __syncthreads();
    {
        const size_t off = (size_t)LO(p, p) * 4096;
        for (int idx = tid; idx < 4096; idx += 256) {
            int r = idx >> 6, c = idx & 63;
            double xv = sX[r][c];
            Wp[off + idx] = xv;
            WTp[off + (size_t)c * 64 + r] = xv;
        }
    }
    __syncthreads();
}

__global__ __launch_bounds__(256) void factor0_kernel(const double* __restrict__ A,
                                                      double* __restrict__ Wp,
                                                      double* __restrict__ WTp) {
    __shared__ double smem[9136];
    double (*fA)[65] = (double(*)[65])smem;
    double (*fX)[65] = (double(*)[65])(smem + 4160);
    double* fW = smem + 8320;
    const int tid = threadIdx.x;
    for (int idx = tid; idx < 4096; idx += 256) {
        int r = idx >> 6, c = idx & 63;
        fA[r][c] = (c <= r) ? A[(size_t)r * 512 + c] : 0.0;
    }
    __syncthreads();
    factor64(fA, fX, fW, Wp, WTp, 0);
}

// ---------------------------------------------------------------------------
// trailing-update tile for panel p (tile engine): recompute L_Ip, L_Jp;
// diag blocks publish L tile (I,p) to LL; update A_IJ; block (0,0) factors
// panel p+1 in place.
// ---------------------------------------------------------------------------
__device__ void upd_tile(double* smem, double* A, double* LL,
                         double* Wp, double* WTp, int p, int s, int tx, int ty) {
    double* T0 = smem;
    double* T1 = smem + 4096;
    double* T2 = smem + 8192;
    int bi = 0;
    while (s >= bi + 1) { s -= bi + 1; ++bi; }
    const int bj = s;
    const int I = p + 1 + bi, J = p + 1 + bj;
    const bool diag = (I == J);

    stage_tile(T0, A + (size_t)I * 64 * 512 + p * 64, 512, 64);
    if (!diag) stage_tile(T1, A + (size_t)J * 64 * 512 + p * 64, 512, 64);
    stage_tile(T2, Wp + (size_t)LO(p, p) * 4096, 64, 64);   // Dinv_p: T2[c][t]=X[c][t]
    __syncthreads();

    double lip[4][4] = {}, ljp[4][4] = {};
    mac4x4(T0, T2, lip, tx, ty);                             // L_Ip = A_Ip · X^T
    if (!diag) mac4x4(T1, T2, ljp, tx, ty);
    __syncthreads();
    stt_tile(T0, lip, tx, ty);
    if (!diag) stt_tile(T1, ljp, tx, ty);
    if (diag) {                                              // publish L tile (I,p)
#pragma unroll
        for (int r = 0; r < 4; ++r)
#pragma unroll
            for (int c = 0; c < 4; ++c)
                LL[(size_t)(I * 64 + 4 * ty + r) * 512 + p * 64 + 4 * tx + c] = lip[r][c];
    }
    __syncthreads();

    double acc[4][4] = {};
    mac4x4(T0, diag ? T0 : T1, acc, tx, ty);                 // L_Ip · L_Jp^T

    double* Aij = A + (size_t)I * 64 * 512 + (size_t)J * 64;
    if (bi == 0 && bj == 0) {
        __syncthreads();
        double (*fA)[65] = (double(*)[65])smem;
        double (*fX)[65] = (double(*)[65])(smem + 4160);
        double* fW = smem + 8320;
#pragma unroll
        for (int r = 0; r < 4; ++r)
#pragma unroll
            for (int c = 0; c < 4; ++c) {
                int rr = 4 * ty + r, cc = 4 * tx + c;
                fA[rr][cc] = (cc <= rr) ? (Aij[(size_t)rr * 512 + cc] - acc[r][c]) : 0.0;
            }
        __syncthreads();
        factor64(fA, fX, fW, Wp, WTp, p + 1);
    } else {
#pragma unroll
        for (int r = 0; r < 4; ++r)
#pragma unroll
            for (int c = 0; c < 4; ++c) {
                int rr = 4 * ty + r, cc = 4 * tx + c;
                if (!diag || cc <= rr)
                    Aij[(size_t)rr * 512 + cc] -= acc[r][c];
            }
    }
}

// W row-panel p tile J (J<p): X_pJ = -Dinv_p * sum_{K=J..p-1} L_pK * X_KJ
__device__ void wrow_tile(double* smem, const double* LL,
                          double* Wp, double* WTp, int p, int J, int tx, int ty) {
    double* T0 = smem;
    double* T1 = smem + 4096;
    double* T2 = smem + 8192;
    stage_tile(T2, Wp + (size_t)LO(p, p) * 4096, 64, 64);    // Dinv_p
    double S[4][4] = {};
    for (int K = J; K < p; ++K) {
        stage_tile(T0, LL + (size_t)(p * 64) * 512 + K * 64, 512, 64);   // L_pK rows
        stage_tile(T1, WTp + (size_t)LO(K, J) * 4096, 64, 64);           // T1[a][b]=X_KJ[b][a]
        __syncthreads();
        mac4x4(T0, T1, S, tx, ty);                           // S += L_pK · X_KJ
        __syncthreads();
    }
    // store S transposed into T0: T0[c'][t'] = S_glob[t'][c']
#pragma unroll
    for (int c = 0; c < 4; ++c)
#pragma unroll
        for (int rp = 0; rp < 2; ++rp)
            st2t(T0, 4 * tx + c, 2 * ty + rp, S[2 * rp][c], S[2 * rp + 1][c]);
    __syncthreads();
    double X[4][4] = {};
    mac4x4(T2, T0, X, tx, ty);                               // Dinv_p · S
    const size_t wo = (size_t)LO(p, J) * 4096;
#pragma unroll
    for (int r = 0; r < 4; ++r)
#pragma unroll
        for (int c = 0; c < 4; ++c) {
            Wp[wo + (size_t)(4 * ty + r) * 64 + 4 * tx + c] = -X[r][c];
            WTp[wo + (size_t)(4 * tx + c) * 64 + 4 * ty + r] = -X[r][c];
        }
}

// upd launch p: blocks [0,nupd) trailing tiles; [nupd, nupd+p) W row-panel p
__global__ __launch_bounds__(256) void upd_kernel(double* __restrict__ A,
                                                  double* __restrict__ LL,
                                                  double* __restrict__ Wp,
                                                  double* __restrict__ WTp,
                                                  int p) {
    __shared__ double smem[12288];
    const int tx = threadIdx.x & 15, ty = threadIdx.x >> 4;
    const int nupd = (7 - p) * (8 - p) / 2;
    if ((int)blockIdx.x < nupd)
        upd_tile(smem, A, LL, Wp, WTp, p, blockIdx.x, tx, ty);
    else
        wrow_tile(smem, LL, Wp, WTp, p, blockIdx.x - nupd, tx, ty);
}

__global__ __launch_bounds__(256) void wrow7_kernel(const double* __restrict__ LL,
                                                    double* __restrict__ Wp,
                                                    double* __restrict__ WTp) {
    __shared__ double smem[12288];
    const int tx = threadIdx.x & 15, ty = threadIdx.x >> 4;
    wrow_tile(smem, LL, Wp, WTp, 7, blockIdx.x, tx, ty);
}

// ---------------------------------------------------------------------------
// GEMMs: T = W*B, then Z = W^T*T. B,T,Z col-major [col][512].
// ---------------------------------------------------------------------------
__global__ __launch_bounds__(256) void gemm1_kernel(const double* __restrict__ Wp,
                                                    const double* __restrict__ Bc,
                                                    double* __restrict__ Tbuf) {
    __shared__ double smem[8192];
    const int blk = blockIdx.x;
    const int i = blk / 5, ct = blk % 5, c0 = ct * 64;
    const int nr = (257 - c0 < 64) ? (257 - c0) : 64;
    double* T0 = smem;
    double* T1 = smem + 4096;
    const int tx = threadIdx.x & 15, ty = threadIdx.x >> 4;
    double acc[4][4] = {};
    for (int j = 0; j <= i; ++j) {
        stage_tile(T0, Wp + (size_t)LO(i, j) * 4096, 64, 64);
        stage_tile(T1, Bc + (size_t)c0 * 512 + j * 64, 512, nr);
        __syncthreads();
        mac4x4(T0, T1, acc, tx, ty);
        __syncthreads();
    }
#pragma unroll
    for (int r = 0; r < 4; ++r)
#pragma unroll
        for (int c = 0; c < 4; ++c) {
            int cc = c0 + 4 * tx + c;
            if (cc < 257) Tbuf[(size_t)cc * 512 + i * 64 + 4 * ty + r] = acc[r][c];
        }
}

__global__ __launch_bounds__(256) void gemm2_kernel(const double* __restrict__ WTp,
                                                    const double* __restrict__ Tbuf,
                                                    double* __restrict__ Bc) {
    __shared__ double smem[8192];
    const int blk = blockIdx.x;
    const int i = blk / 5, ct = blk % 5, c0 = ct * 64;
    const int nr = (257 - c0 < 64) ? (257 - c0) : 64;
    double* T0 = smem;
    double* T1 = smem + 4096;
    const int tx = threadIdx.x & 15, ty = threadIdx.x >> 4;
    double acc[4][4] = {};
    for (int j = i; j < 8; ++j) {
        stage_tile(T0, WTp + (size_t)LO(j, i) * 4096, 64, 64);   // T0[a][t]=W[j64+t][i64+a]
        stage_tile(T1, Tbuf + (size_t)c0 * 512 + j * 64, 512, nr);
        __syncthreads();
        mac4x4(T0, T1, acc, tx, ty);
        __syncthreads();
    }
#pragma unroll
    for (int r = 0; r < 4; ++r)
#pragma unroll
        for (int c = 0; c < 4; ++c) {
            int cc = c0 + 4 * tx + c;
            if (cc < 257) Bc[(size_t)cc * 512 + i * 64 + 4 * ty + r] = acc[r][c];
        }
}

// column reductions over Z (col-major [257][512]); 4 cols per block
__global__ __launch_bounds__(256) void colreduce_kernel(const double* __restrict__ Z,
                                                        const float* __restrict__ ys,
                                                        const float* __restrict__ b_p,
                                                        float* __restrict__ out,
                                                        double* __restrict__ kbx,
                                                        double* __restrict__ Sp) {
    const int lane = threadIdx.x & 63, w = threadIdx.x >> 6;
    const int c = blockIdx.x * 4 + w;
    if (c >= 257) return;
    const double b = (double)b_p[0];
    double s0 = 0.0, s1 = 0.0;
#pragma unroll
    for (int t = 0; t < 8; ++t) {
        int n = lane + 64 * t;
        double zv = Z[(size_t)c * 512 + n];
        s0 += zv;
        s1 = fma(zv, (double)ys[n] - b, s1);
    }
#pragma unroll
    for (int off = 1; off < 64; off <<= 1) {
        s0 += __shfl_xor(s0, off, 64);
        s1 += __shfl_xor(s1, off, 64);
    }
    if (lane == 0) {
        if (c < 256) { out[c] = (float)(b + s1); kbx[c] = s0; }
        else Sp[0] = s0;
    }
}

// cov[i][j] = Kxx[i][j] - sum_n Z[i][n]*Kox[n][j] + (1-kbx[i])(1-kbx[j])/S
__global__ __launch_bounds__(256) void cov_kernel(const double* __restrict__ Z,
                                                  const float* __restrict__ KoxT,
                                                  const float* __restrict__ Kxx,
                                                  const double* __restrict__ kbx,
                                                  const double* __restrict__ Sp,
                                                  float* __restrict__ out) {
    __shared__ double smem[8192];
    const int bi = blockIdx.x >> 2, bj = blockIdx.x & 3;
    double* T0 = smem;
    double* T1 = smem + 4096;
    const int tx = threadIdx.x & 15, ty = threadIdx.x >> 4;
    double acc[4][4] = {};
    for (int kt = 0; kt < 8; ++kt) {
        stage_tile(T0, Z + (size_t)(bi * 64) * 512 + kt * 64, 512, 64);
        stage_tile_f(T1, KoxT + (size_t)(bj * 64) * 512 + kt * 64, 512);
        __syncthreads();
        mac4x4(T0, T1, acc, tx, ty);
        __syncthreads();
    }
    const double S = Sp[0];
#pragma unroll
    for (int r = 0; r < 4; ++r) {
        int i = bi * 64 + 4 * ty + r;
        double ki = 1.0 - kbx[i];
#pragma unroll
        for (int c = 0; c < 4; ++c) {
            int j = bj * 64 + 4 * tx + c;
            double corr = ki * (1.0 - kbx[j]) / S;
            out[(size_t)(1 + i) * 256 + j] =
                (float)((double)Kxx[(size_t)i * 256 + j] - acc[r][c] + corr);
        }
    }
}

// ---------------------------------------------------------------------------
extern "C" void kernel_launch(void* const* d_in, const int* in_sizes, int n_in,
                              void* d_out, int out_size, void* d_ws, size_t ws_size,
                              hipStream_t stream) {
    const float* X_test = (const float*)d_in[0];
    const float* A_test = (const float*)d_in[1];
    const float* X_obs  = (const float*)d_in[2];
    const float* A_obs  = (const float*)d_in[3];
    const float* ys     = (const float*)d_in[4];
    const float* rho_p  = (const float*)d_in[5];
    const float* g_p    = (const float*)d_in[6];
    const float* nu_p   = (const float*)d_in[7];
    const float* b_p    = (const float*)d_in[8];
    float* out = (float*)d_out;
    char* ws = (char*)d_ws;

    double* Koo  = (double*)(ws + 0);         // 2,097,152 (A; Tbuf alias post-chol)
    double* LL   = (double*)(ws + 2097152);   // 2,097,152 (L row-major; atT/atO overlay pre-chol)
    double* Bc   = (double*)(ws + 4194304);   // 1,052,672 (RHS -> Z)
    float*  KoxT = (float*) (ws + 5246976);   // 524,288
    float*  Kxx  = (float*) (ws + 5771264);   // 262,144
    float*  s1v  = (float*) (ws + 6033408);   // 1,024
    float*  s2v  = (float*) (ws + 6034432);   // 2,048
    double* kbx  = (double*)(ws + 6036480);   // 2,048
    double* Sp   = (double*)(ws + 6038528);   // 1,024 (pad)
    double* Wp   = (double*)(ws + 6039552);   // 36*32768 = 1,179,648
    double* WTp  = (double*)(ws + 7219200);   // 1,179,648 (end 8,398,848)
    double* Tbuf = Koo;                       // aliases dead A after chol
    float*  atT  = (float*)(ws + 2097152);
    float*  atO  = (float*)(ws + 2097152 + 24576);

    self_kernel<<<M + N + 1, 64, 0, stream>>>(X_test, A_test, X_obs, A_obs,
                                              s1v, s2v, atT, atO, Bc);

    gram_kernel<<<dim3(32, 64, 3), 128, 0, stream>>>(X_test, atT, s1v,
                                                     X_obs, atO, s2v,
                                                     rho_p, nu_p, g_p,
                                                     KoxT, Kxx, Koo, Bc);

    factor0_kernel<<<1, 256, 0, stream>>>(Koo, Wp, WTp);
    for (int p = 0; p < 7; ++p) {
        int nb = (7 - p) * (8 - p) / 2 + p;   // trailing tiles + W row-panel p
        upd_kernel<<<nb, 256, 0, stream>>>(Koo, LL, Wp, WTp, p);
    }
    wrow7_kernel<<<7, 256, 0, stream>>>(LL, Wp, WTp);

    gemm1_kernel<<<40, 256, 0, stream>>>(Wp, Bc, Tbuf);
    gemm2_kernel<<<40, 256, 0, stream>>>(WTp, Tbuf, Bc);
    colreduce_kernel<<<65, 256, 0, stream>>>(Bc, ys, b_p, out, kbx, Sp);
    cov_kernel<<<16, 256, 0, stream>>>(Bc, KoxT, Kxx, kbx, Sp, out);
}

// Round 13
// 902.911 us; speedup vs baseline: 1.3153x; 1.0802x over previous
//
#include <hip/hip_runtime.h>
#include <cmath>

// Problem constants
#define M 256
#define N 512
#define P 24
#define D 8

// ---------------------------------------------------------------------------
// self terms + folded weights at[i,u] = A[i,u]*exp(-0.5*||x_iu||^2).
// Block M+N writes the ones-column of Bc.
// ---------------------------------------------------------------------------
__global__ __launch_bounds__(64) void self_kernel(const float* __restrict__ X_test,
                                                  const float* __restrict__ A_test,
                                                  const float* __restrict__ X_obs,
                                                  const float* __restrict__ A_obs,
                                                  float* __restrict__ s1,
                                                  float* __restrict__ s2,
                                                  float* __restrict__ atT,
                                                  float* __restrict__ atO,
                                                  double* __restrict__ Bc) {
    const int bid = blockIdx.x;
    const int lane = threadIdx.x;
    if (bid == M + N) {  // ones column (col 256 of Bc, col-major [257][512])
#pragma unroll
        for (int t = 0; t < 8; ++t) Bc[(size_t)256 * 512 + 64 * t + lane] = 1.0;
        return;
    }
    const float* X; const float* A; float* s; float* at; int i;
    if (bid < M) { X = X_test; A = A_test; s = s1; at = atT; i = bid; }
    else         { X = X_obs;  A = A_obs;  s = s2; at = atO; i = bid - M; }
    const float* Xi = X + (size_t)i * P * D;
    const float* Ai = A + (size_t)i * P;
    float acc = 0.f;
#pragma unroll
    for (int t = 0; t < 9; ++t) {
        int idx = lane + 64 * t;          // 0..575
        int u = idx / 24;
        int v = idx - u * 24;
        const float* xu = Xi + u * D;
        const float* xv = Xi + v * D;
        float d2 = 0.f;
#pragma unroll
        for (int d = 0; d < D; ++d) { float df = xu[d] - xv[d]; d2 = fmaf(df, df, d2); }
        acc = fmaf(Ai[u] * Ai[v], __expf(-0.5f * d2), acc);
    }
#pragma unroll
    for (int off = 1; off < 64; off <<= 1) acc += __shfl_xor(acc, off, 64);
    if (lane == 0) s[i] = acc;
    if (lane < 24) {
        const float* xp = Xi + lane * D;
        float q = 0.f;
#pragma unroll
        for (int d = 0; d < D; ++d) q = fmaf(xp[d], xp[d], q);
        at[(size_t)i * P + lane] = Ai[lane] * __expf(-0.5f * q);
    }
}

// ---------------------------------------------------------------------------
// fused gram kernel with norm-folded weights (unchanged from r12)
// ---------------------------------------------------------------------------
__global__ __launch_bounds__(128) void gram_kernel(
    const float* __restrict__ Xt, const float* __restrict__ atT, const float* __restrict__ s1,
    const float* __restrict__ Xo, const float* __restrict__ atO, const float* __restrict__ s2,
    const float* __restrict__ rho_p, const float* __restrict__ nu_p, const float* __restrict__ g_p,
    float* __restrict__ KoxT, float* __restrict__ Kxx, double* __restrict__ Koo,
    double* __restrict__ Bc) {
    const int mode = blockIdx.z;
    const int it = blockIdx.x, jt = blockIdx.y;
    const float *X1, *AT1, *S1, *X2, *AT2, *S2;
    if (mode == 0) {
        if (jt > 2 * it + 1) return;
        X1 = Xo; AT1 = atO; S1 = s2; X2 = Xo; AT2 = atO; S2 = s2;
    } else if (mode == 1) {
        if (jt >= 32) return;
        X1 = Xo; AT1 = atO; S1 = s2; X2 = Xt; AT2 = atT; S2 = s1;
    } else {
        if (it >= 16 || jt >= 32 || jt < 2 * it) return;
        X1 = Xt; AT1 = atT; S1 = s1; X2 = Xt; AT2 = atT; S2 = s1;
    }
    const int i0 = it * 16, j0 = jt * 8;
    const int tid = threadIdx.x;
    const int il = tid >> 3, uc = tid & 7;
    const int i = i0 + il;

    __shared__ __align__(16) float X2s[8 * 192];
    __shared__ float A2s[8 * 24];
    __shared__ float S2s[8];
    {
        const float4* gx = (const float4*)(X2 + (size_t)j0 * 192);
        float4* lx = (float4*)X2s;
        for (int idx = tid; idx < 8 * 48; idx += 128) lx[idx] = gx[idx];
        for (int idx = tid; idx < 8 * 24; idx += 128) A2s[idx] = AT2[(size_t)j0 * 24 + idx];
        if (tid < 8) S2s[tid] = S2[j0 + tid];
    }
    __syncthreads();

    float x1r[3][8], at1r[3];
#pragma unroll
    for (int ss = 0; ss < 3; ++ss) {
        const float* p = X1 + ((size_t)i * P + uc * 3 + ss) * D;
#pragma unroll
        for (int d = 0; d < D; ++d) x1r[ss][d] = p[d];
        at1r[ss] = AT1[(size_t)i * P + uc * 3 + ss];
    }
    const float s1i = S1[i];
    const float rho = rho_p[0], nu = nu_p[0], g = g_p[0];

    for (int jj = 0; jj < 8; ++jj) {
        const float* xb = X2s + jj * 192;
        float e0 = 0.f, e1 = 0.f, e2 = 0.f;
#pragma unroll 4
        for (int v = 0; v < 24; ++v) {
            const float4 q0 = ((const float4*)(xb + v * 8))[0];
            const float4 q1 = ((const float4*)(xb + v * 8))[1];
            float x2r[8];
            x2r[0] = q0.x; x2r[1] = q0.y; x2r[2] = q0.z; x2r[3] = q0.w;
            x2r[4] = q1.x; x2r[5] = q1.y; x2r[6] = q1.z; x2r[7] = q1.w;
            const float w2 = A2s[jj * 24 + v];
            float d0 = 0.f, d1 = 0.f, d2 = 0.f;
#pragma unroll
            for (int dd = 0; dd < 8; ++dd) {
                d0 = fmaf(x1r[0][dd], x2r[dd], d0);
                d1 = fmaf(x1r[1][dd], x2r[dd], d1);
                d2 = fmaf(x1r[2][dd], x2r[dd], d2);
            }
            e0 = fmaf(w2, __expf(d0), e0);
            e1 = fmaf(w2, __expf(d1), e1);
            e2 = fmaf(w2, __expf(d2), e2);
        }
        float acc = at1r[0] * e0;
        acc = fmaf(at1r[1], e1, acc);
        acc = fmaf(at1r[2], e2, acc);
        acc += __shfl_xor(acc, 1, 8);
        acc += __shfl_xor(acc, 2, 8);
        acc += __shfl_xor(acc, 4, 8);
        if (uc == 0) {
            const int j = j0 + jj;
            float d2p = fmaxf(s1i + S2s[jj] - 2.f * acc, 0.f);
            float kv = __expf(-0.5f * d2p / rho);
            if (mode == 0) {
                if (j <= i) Koo[(size_t)i * 512 + j] = (double)(nu * (kv + ((i == j) ? g : 0.f)));
            } else if (mode == 1) {
                float val = nu * kv;
                KoxT[(size_t)j * 512 + i] = val;
                Bc[(size_t)j * 512 + i] = (double)val;
            } else {
                float val = nu * kv;
                if (j >= i) {
                    Kxx[(size_t)i * 256 + j] = val;
                    if (j > i) Kxx[(size_t)j * 256 + i] = val;
                }
            }
        }
    }
}

// ---------------------------------------------------------------------------
// Conflict-free 64x64 f64 tile engine (r12, unchanged).
// ---------------------------------------------------------------------------
__device__ __forceinline__ double2 ld2t(const double* T, int r, int m) {
    return *(const double2*)(T + r * 64 + 2 * ((m ^ (r >> 2)) & 31));
}
__device__ __forceinline__ void st2t(double* T, int r, int m, double x, double y) {
    double2 v; v.x = x; v.y = y;
    *(double2*)(T + r * 64 + 2 * ((m ^ (r >> 2)) & 31)) = v;
}

__device__ void stage_tile(double* T, const double* G, int ldg, int nrows) {
    const int tid = threadIdx.x;
#pragma unroll
    for (int e = 0; e < 8; ++e) {
        int idx = tid + 256 * e, r = idx >> 5, m = idx & 31;
        double x = 0.0, y = 0.0;
        if (r < nrows) {
            double2 v = *(const double2*)(G + (size_t)r * ldg + 2 * m);
            x = v.x; y = v.y;
        }
        st2t(T, r, m, x, y);
    }
}
__device__ void stage_tile_f(double* T, const float* G, int ldg) {
    const int tid = threadIdx.x;
#pragma unroll
    for (int e = 0; e < 8; ++e) {
        int idx = tid + 256 * e, r = idx >> 5, m = idx & 31;
        float2 v = *(const float2*)(G + (size_t)r * ldg + 2 * m);
        st2t(T, r, m, (double)v.x, (double)v.y);
    }
}

// acc[r][c] += sum_t At[4ty+r][t] * Bt[4tx+c][t]
__device__ __forceinline__ void mac4x4(const double* At, const double* Bt,
                                       double acc[4][4], int tx, int ty) {
#pragma unroll 4
    for (int m = 0; m < 32; ++m) {
        double2 a[4], b[4];
#pragma unroll
        for (int j = 0; j < 4; ++j) a[j] = ld2t(At, 4 * ty + j, m);
#pragma unroll
        for (int j = 0; j < 4; ++j) b[j] = ld2t(Bt, 4 * tx + j, m);
#pragma unroll
        for (int r = 0; r < 4; ++r)
#pragma unroll
            for (int c = 0; c < 4; ++c)
                acc[r][c] = fma(a[r].y, b[c].y, fma(a[r].x, b[c].x, acc[r][c]));
    }
}

__device__ void stt_tile(double* T, const double v[4][4], int tx, int ty) {
#pragma unroll
    for (int r = 0; r < 4; ++r)
#pragma unroll
        for (int mp = 0; mp < 2; ++mp)
            st2t(T, 4 * ty + r, 2 * tx + mp, v[r][2 * mp], v[r][2 * mp + 1]);
}

#define LO(i, j) ((i) * ((i) + 1) / 2 + (j))   // packed lower-tile index (i>=j)

// ---------------------------------------------------------------------------
// fast f64 reciprocal / rsqrt via HW estimate + Newton (v_rcp_f64 ~26 bits,
// two quadratic refinements -> full double). d > 0 guaranteed (SPD + jitter).
// ---------------------------------------------------------------------------
__device__ __forceinline__ double frcp(double d) {
    double r;
    asm("v_rcp_f64 %0, %1" : "=v"(r) : "v"(d));
    double e = fma(-d, r, 1.0); r = fma(r, e, r);
    e = fma(-d, r, 1.0); r = fma(r, e, r);
    return r;
}
__device__ __forceinline__ double frsq(double d) {
    double r;
    asm("v_rsq_f64 %0, %1" : "=v"(r) : "v"(d));
    double t = -0.5 * d * r; r = r * fma(t, r, 1.5);
    t = -0.5 * d * r; r = r * fma(t, r, 1.5);
    return r;
}

// ---------------------------------------------------------------------------
// factor64 v3: single-wave (tid<64), row-per-lane in REGISTERS, fully
// unrolled LDL elimination (LDS column broadcast, Newton rcp) + unit-lower
// inverse (Lu in LDS, x in registers, no divisions). ~15us vs ~85us for the
// r10 shfl/bpermute version. Writes X = inv(L_chol) to packed Wp/WTp tile p.
// sA: plain [64][65] LDS, LOWER triangle valid (upper never read).
// colbuf: 64-double LDS scratch. Caller must __syncthreads() after filling
// sA and guard with (tid < 64). No barriers inside (single wave).
// ---------------------------------------------------------------------------
__device__ void factor64v3(double* sA, double* colbuf,
                           double* __restrict__ Wp, double* __restrict__ WTp,
                           int p) {
    const int lane = threadIdx.x;
    double a[64];
#pragma unroll
    for (int c = 0; c < 64; ++c) {
        int ad = (c <= lane) ? (lane * 65 + c) : (c * 65 + lane);  // mirror upper
        a[c] = sA[ad];
    }
    double myinv = 0.0, myd = 1.0;
    // LDL elimination, deferred scale: after loop, a[c] (c<=lane) = Lu[r][c]*d_c
#pragma unroll
    for (int k = 0; k < 64; ++k) {
        colbuf[lane] = a[k];                    // column k broadcast (in-wave order)
        double dk = colbuf[k];
        double inv = frcp(dk);
        if (lane == k) { myinv = inv; myd = dk; }
        double s = (lane > k) ? a[k] * inv : 0.0;
#pragma unroll
        for (int c = k + 1; c < 64; ++c)
            a[c] = fma(-s, colbuf[c], a[c]);
    }
    const double myrs = frsq(myd);              // 1/sqrt(d_lane)
    // scale columns to unit-lower Lu: Lu[r][c] = a[c] * invd_c
    colbuf[lane] = myinv;
#pragma unroll
    for (int c = 0; c < 64; ++c) a[c] *= colbuf[c];
    // park Lu rows in LDS (frees a[] for x[])
#pragma unroll
    for (int c = 0; c < 64; ++c) sA[lane * 65 + c] = a[c];
    // x = column `lane` of Yu = inv(Lu):  x[r] = delta - sum_{t<r} Lu[r][t] x[t]
#pragma unroll
    for (int r = 0; r < 64; ++r) a[r] = (lane == r) ? 1.0 : 0.0;
#pragma unroll
    for (int r = 1; r < 64; ++r) {
        const double* Lr = sA + r * 65;
        double a0 = 0.0, a1 = 0.0, a2 = 0.0, a3 = 0.0;
#pragma unroll
        for (int t = 0; t < r; ++t) {
            double lv = Lr[t];
            if ((t & 3) == 0) a0 = fma(lv, a[t], a0);
            else if ((t & 3) == 1) a1 = fma(lv, a[t], a1);
            else if ((t & 3) == 2) a2 = fma(lv, a[t], a2);
            else a3 = fma(lv, a[t], a3);
        }
        a[r] -= (a0 + a1) + (a2 + a3);
    }
    // X = S^{-1} Yu: row scale by rs_r
    colbuf[lane] = myrs;
#pragma unroll
    for (int r = 0; r < 64; ++r) a[r] *= colbuf[r];
    // outputs: Wp[r][c] coalesced per row; WTp row `lane` contiguous
    const size_t off = (size_t)LO(p, p) * 4096;
#pragma unroll
    for (int r = 0; r < 64; ++r) Wp[off + (size_t)r * 64 + lane] = a[r];
#pragma unroll
    for (int r = 0; r < 64; r += 2) {
        double2 v; v.x = a[r]; v.y = a[r + 1];
        *(double2*)(WTp + off + (size_t)lane * 64 + r) = v;
    }
}

__global__ __launch_bounds__(256) void factor0_kernel(const double* __restrict__ A,
                                                      double* __restrict__ Wp,
                                                      double* __restrict__ WTp) {
    __shared__ double smem[4160 + 64];
    const int tid = threadIdx.x;
    for (int idx = tid; idx < 4096; idx += 256) {
        int r = idx >> 6, c = idx & 63;
        if (c <= r) smem[r * 65 + c] = A[(size_t)r * 512 + c];
    }
    __syncthreads();
    if (tid < 64) factor64v3(smem, smem + 4160, Wp, WTp, 0);
}

// ---------------------------------------------------------------------------
// trailing-update tile for panel p (tile engine, r12): recompute L_Ip, L_Jp;
// diag blocks publish L tile (I,p) to LL; update A_IJ; block (0,0) factors
// panel p+1 in place via factor64v3.
// ---------------------------------------------------------------------------
__device__ void upd_tile(double* smem, double* A, double* LL,
                         double* Wp, double* WTp, int p, int s, int tx, int ty) {
    double* T0 = smem;
    double* T1 = smem + 4096;
    double* T2 = smem + 8192;
    int bi = 0;
    while (s >= bi + 1) { s -= bi + 1; ++bi; }
    const int bj = s;
    const int I = p + 1 + bi, J = p + 1 + bj;
    const bool diag = (I == J);

    stage_tile(T0, A + (size_t)I * 64 * 512 + p * 64, 512, 64);
    if (!diag) stage_tile(T1, A + (size_t)J * 64 * 512 + p * 64, 512, 64);
    stage_tile(T2, Wp + (size_t)LO(p, p) * 4096, 64, 64);   // Dinv_p: T2[c][t]=X[c][t]
    __syncthreads();

    double lip[4][4] = {}, ljp[4][4] = {};
    mac4x4(T0, T2, lip, tx, ty);                             // L_Ip = A_Ip · X^T
    if (!diag) mac4x4(T1, T2, ljp, tx, ty);
    __syncthreads();
    stt_tile(T0, lip, tx, ty);
    if (!diag) stt_tile(T1, ljp, tx, ty);
    if (diag) {                                              // publish L tile (I,p)
#pragma unroll
        for (int r = 0; r < 4; ++r)
#pragma unroll
            for (int c = 0; c < 4; ++c)
                LL[(size_t)(I * 64 + 4 * ty + r) * 512 + p * 64 + 4 * tx + c] = lip[r][c];
    }
    __syncthreads();

    double acc[4][4] = {};
    mac4x4(T0, diag ? T0 : T1, acc, tx, ty);                 // L_Ip · L_Jp^T

    double* Aij = A + (size_t)I * 64 * 512 + (size_t)J * 64;
    if (bi == 0 && bj == 0) {
        __syncthreads();
        // write updated diag tile (lower) to plain [64][65] at smem
#pragma unroll
        for (int r = 0; r < 4; ++r)
#pragma unroll
            for (int c = 0; c < 4; ++c) {
                int rr = 4 * ty + r, cc = 4 * tx + c;
                if (cc <= rr) smem[rr * 65 + cc] = Aij[(size_t)rr * 512 + cc] - acc[r][c];
            }
        __syncthreads();
        if (threadIdx.x < 64) factor64v3(smem, smem + 4160, Wp, WTp, p + 1);
    } else {
#pragma unroll
        for (int r = 0; r < 4; ++r)
#pragma unroll
            for (int c = 0; c < 4; ++c) {
                int rr = 4 * ty + r, cc = 4 * tx + c;
                if (!diag || cc <= rr)
                    Aij[(size_t)rr * 512 + cc] -= acc[r][c];
            }
    }
}

// W row-panel p tile J (J<p): X_pJ = -Dinv_p * sum_{K=J..p-1} L_pK * X_KJ
__device__ void wrow_tile(double* smem, const double* LL,
                          double* Wp, double* WTp, int p, int J, int tx, int ty) {
    double* T0 = smem;
    double* T1 = smem + 4096;
    double* T2 = smem + 8192;
    stage_tile(T2, Wp + (size_t)LO(p, p) * 4096, 64, 64);    // Dinv_p
    double S[4][4] = {};
    for (int K = J; K < p; ++K) {
        stage_tile(T0, LL + (size_t)(p * 64) * 512 + K * 64, 512, 64);   // L_pK rows
        stage_tile(T1, WTp + (size_t)LO(K, J) * 4096, 64, 64);           // T1[a][b]=X_KJ[b][a]
        __syncthreads();
        mac4x4(T0, T1, S, tx, ty);                           // S += L_pK · X_KJ
        __syncthreads();
    }
    // store S transposed into T0: T0[c'][t'] = S_glob[t'][c']
#pragma unroll
    for (int c = 0; c < 4; ++c)
#pragma unroll
        for (int rp = 0; rp < 2; ++rp)
            st2t(T0, 4 * tx + c, 2 * ty + rp, S[2 * rp][c], S[2 * rp + 1][c]);
    __syncthreads();
    double X[4][4] = {};
    mac4x4(T2, T0, X, tx, ty);                               // Dinv_p · S
    const size_t wo = (size_t)LO(p, J) * 4096;
#pragma unroll
    for (int r = 0; r < 4; ++r)
#pragma unroll
        for (int c = 0; c < 4; ++c) {
            Wp[wo + (size_t)(4 * ty + r) * 64 + 4 * tx + c] = -X[r][c];
            WTp[wo + (size_t)(4 * tx + c) * 64 + 4 * ty + r] = -X[r][c];
        }
}

// upd launch p: blocks [0,nupd) trailing tiles; [nupd, nupd+p) W row-panel p
__global__ __launch_bounds__(256) void upd_kernel(double* __restrict__ A,
                                                  double* __restrict__ LL,
                                                  double* __restrict__ Wp,
                                                  double* __restrict__ WTp,
                                                  int p) {
    __shared__ double smem[12288];
    const int tx = threadIdx.x & 15, ty = threadIdx.x >> 4;
    const int nupd = (7 - p) * (8 - p) / 2;
    if ((int)blockIdx.x < nupd)
        upd_tile(smem, A, LL, Wp, WTp, p, blockIdx.x, tx, ty);
    else
        wrow_tile(smem, LL, Wp, WTp, p, blockIdx.x - nupd, tx, ty);
}

__global__ __launch_bounds__(256) void wrow7_kernel(const double* __restrict__ LL,
                                                    double* __restrict__ Wp,
                                                    double* __restrict__ WTp) {
    __shared__ double smem[12288];
    const int tx = threadIdx.x & 15, ty = threadIdx.x >> 4;
    wrow_tile(smem, LL, Wp, WTp, 7, blockIdx.x, tx, ty);
}

// ---------------------------------------------------------------------------
// GEMMs: T = W*B, then Z = W^T*T. B,T,Z col-major [col][512].
// ---------------------------------------------------------------------------
__global__ __launch_bounds__(256) void gemm1_kernel(const double* __restrict__ Wp,
                                                    const double* __restrict__ Bc,
                                                    double* __restrict__ Tbuf) {
    __shared__ double smem[8192];
    const int blk = blockIdx.x;
    const int i = blk / 5, ct = blk % 5, c0 = ct * 64;
    const int nr = (257 - c0 < 64) ? (257 - c0) : 64;
    double* T0 = smem;
    double* T1 = smem + 4096;
    const int tx = threadIdx.x & 15, ty = threadIdx.x >> 4;
    double acc[4][4] = {};
    for (int j = 0; j <= i; ++j) {
        stage_tile(T0, Wp + (size_t)LO(i, j) * 4096, 64, 64);
        stage_tile(T1, Bc + (size_t)c0 * 512 + j * 64, 512, nr);
        __syncthreads();
        mac4x4(T0, T1, acc, tx, ty);
        __syncthreads();
    }
#pragma unroll
    for (int r = 0; r < 4; ++r)
#pragma unroll
        for (int c = 0; c < 4; ++c) {
            int cc = c0 + 4 * tx + c;
            if (cc < 257) Tbuf[(size_t)cc * 512 + i * 64 + 4 * ty + r] = acc[r][c];
        }
}

__global__ __launch_bounds__(256) void gemm2_kernel(const double* __restrict__ WTp,
                                                    const double* __restrict__ Tbuf,
                                                    double* __restrict__ Bc) {
    __shared__ double smem[8192];
    const int blk = blockIdx.x;
    const int i = blk / 5, ct = blk % 5, c0 = ct * 64;
    const int nr = (257 - c0 < 64) ? (257 - c0) : 64;
    double* T0 = smem;
    double* T1 = smem + 4096;
    const int tx = threadIdx.x & 15, ty = threadIdx.x >> 4;
    double acc[4][4] = {};
    for (int j = i; j < 8; ++j) {
        stage_tile(T0, WTp + (size_t)LO(j, i) * 4096, 64, 64);   // T0[a][t]=W[j64+t][i64+a]
        stage_tile(T1, Tbuf + (size_t)c0 * 512 + j * 64, 512, nr);
        __syncthreads();
        mac4x4(T0, T1, acc, tx, ty);
        __syncthreads();
    }
#pragma unroll
    for (int r = 0; r < 4; ++r)
#pragma unroll
        for (int c = 0; c < 4; ++c) {
            int cc = c0 + 4 * tx + c;
            if (cc < 257) Bc[(size_t)cc * 512 + i * 64 + 4 * ty + r] = acc[r][c];
        }
}

// column reductions over Z (col-major [257][512]); 4 cols per block
__global__ __launch_bounds__(256) void colreduce_kernel(const double* __restrict__ Z,
                                                        const float* __restrict__ ys,
                                                        const float* __restrict__ b_p,
                                                        float* __restrict__ out,
                                                        double* __restrict__ kbx,
                                                        double* __restrict__ Sp) {
    const int lane = threadIdx.x & 63, w = threadIdx.x >> 6;
    const int c = blockIdx.x * 4 + w;
    if (c >= 257) return;
    const double b = (double)b_p[0];
    double s0 = 0.0, s1 = 0.0;
#pragma unroll
    for (int t = 0; t < 8; ++t) {
        int n = lane + 64 * t;
        double zv = Z[(size_t)c * 512 + n];
        s0 += zv;
        s1 = fma(zv, (double)ys[n] - b, s1);
    }
#pragma unroll
    for (int off = 1; off < 64; off <<= 1) {
        s0 += __shfl_xor(s0, off, 64);
        s1 += __shfl_xor(s1, off, 64);
    }
    if (lane == 0) {
        if (c < 256) { out[c] = (float)(b + s1); kbx[c] = s0; }
        else Sp[0] = s0;
    }
}

// cov[i][j] = Kxx[i][j] - sum_n Z[i][n]*Kox[n][j] + (1-kbx[i])(1-kbx[j])/S
__global__ __launch_bounds__(256) void cov_kernel(const double* __restrict__ Z,
                                                  const float* __restrict__ KoxT,
                                                  const float* __restrict__ Kxx,
                                                  const double* __restrict__ kbx,
                                                  const double* __restrict__ Sp,
                                                  float* __restrict__ out) {
    __shared__ double smem[8192];
    const int bi = blockIdx.x >> 2, bj = blockIdx.x & 3;
    double* T0 = smem;
    double* T1 = smem + 4096;
    const int tx = threadIdx.x & 15, ty = threadIdx.x >> 4;
    double acc[4][4] = {};
    for (int kt = 0; kt < 8; ++kt) {
        stage_tile(T0, Z + (size_t)(bi * 64) * 512 + kt * 64, 512, 64);
        stage_tile_f(T1, KoxT + (size_t)(bj * 64) * 512 + kt * 64, 512);
        __syncthreads();
        mac4x4(T0, T1, acc, tx, ty);
        __syncthreads();
    }
    const double S = Sp[0];
#pragma unroll
    for (int r = 0; r < 4; ++r) {
        int i = bi * 64 + 4 * ty + r;
        double ki = 1.0 - kbx[i];
#pragma unroll
        for (int c = 0; c < 4; ++c) {
            int j = bj * 64 + 4 * tx + c;
            double corr = ki * (1.0 - kbx[j]) / S;
            out[(size_t)(1 + i) * 256 + j] =
                (float)((double)Kxx[(size_t)i * 256 + j] - acc[r][c] + corr);
        }
    }
}

// ---------------------------------------------------------------------------
extern "C" void kernel_launch(void* const* d_in, const int* in_sizes, int n_in,
                              void* d_out, int out_size, void* d_ws, size_t ws_size,
                              hipStream_t stream) {
    const float* X_test = (const float*)d_in[0];
    const float* A_test = (const float*)d_in[1];
    const float* X_obs  = (const float*)d_in[2];
    const float* A_obs  = (const float*)d_in[3];
    const float* ys     = (const float*)d_in[4];
    const float* rho_p  = (const float*)d_in[5];
    const float* g_p    = (const float*)d_in[6];
    const float* nu_p   = (const float*)d_in[7];
    const float* b_p    = (const float*)d_in[8];
    float* out = (float*)d_out;
    char* ws = (char*)d_ws;

    double* Koo  = (double*)(ws + 0);         // 2,097,152 (A; Tbuf alias post-chol)
    double* LL   = (double*)(ws + 2097152);   // 2,097,152 (L row-major; atT/atO overlay pre-chol)
    double* Bc   = (double*)(ws + 4194304);   // 1,052,672 (RHS -> Z)
    float*  KoxT = (float*) (ws + 5246976);   // 524,288
    float*  Kxx  = (float*) (ws + 5771264);   // 262,144
    float*  s1v  = (float*) (ws + 6033408);   // 1,024
    float*  s2v  = (float*) (ws + 6034432);   // 2,048
    double* kbx  = (double*)(ws + 6036480);   // 2,048
    double* Sp   = (double*)(ws + 6038528);   // 1,024 (pad)
    double* Wp   = (double*)(ws + 6039552);   // 36*32768 = 1,179,648
    double* WTp  = (double*)(ws + 7219200);   // 1,179,648 (end 8,398,848)
    double* Tbuf = Koo;                       // aliases dead A after chol
    float*  atT  = (float*)(ws + 2097152);
    float*  atO  = (float*)(ws + 2097152 + 24576);

    self_kernel<<<M + N + 1, 64, 0, stream>>>(X_test, A_test, X_obs, A_obs,
                                              s1v, s2v, atT, atO, Bc);

    gram_kernel<<<dim3(32, 64, 3), 128, 0, stream>>>(X_test, atT, s1v,
                                                     X_obs, atO, s2v,
                                                     rho_p, nu_p, g_p,
                                                     KoxT, Kxx, Koo, Bc);

    factor0_kernel<<<1, 256, 0, stream>>>(Koo, Wp, WTp);
    for (int p = 0; p < 7; ++p) {
        int nb = (7 - p) * (8 - p) / 2 + p;   // trailing tiles + W row-panel p
        upd_kernel<<<nb, 256, 0, stream>>>(Koo, LL, Wp, WTp, p);
    }
    wrow7_kernel<<<7, 256, 0, stream>>>(LL, Wp, WTp);

    gemm1_kernel<<<40, 256, 0, stream>>>(Wp, Bc, Tbuf);
    gemm2_kernel<<<40, 256, 0, stream>>>(WTp, Tbuf, Bc);
    colreduce_kernel<<<65, 256, 0, stream>>>(Bc, ys, b_p, out, kbx, Sp);
    cov_kernel<<<16, 256, 0, stream>>>(Bc, KoxT, Kxx, kbx, Sp, out);
}